// Round 7
// baseline (613.879 us; speedup 1.0000x reference)
//
#include <hip/hip_runtime.h>
#include <stdint.h>

#define IN_F 4096
#define OUT_F 14336
#define QBLK 64

__device__ __constant__ float NF4_CODE_C[16] = {
    -1.0f, -0.6961928009986877f, -0.5250730514526367f, -0.39491748809814453f,
    -0.28444138169288635f, -0.18477343022823334f, -0.09105003625154495f, 0.0f,
    0.07958029955625534f, 0.16093020141124725f, 0.24611230194568634f,
    0.33791524171829224f, 0.44070982933044434f, 0.5626170039176941f,
    0.8333911895751953f, 1.0f};

typedef __attribute__((ext_vector_type(8))) short short8;   // 8 bf16 (4 VGPRs)
typedef __attribute__((ext_vector_type(4))) float f32x4;    // MFMA acc

__device__ __forceinline__ unsigned short f32_to_bf16_rne(float f) {
    union { float f; uint32_t u; } a; a.f = f;
    uint32_t u = a.u;
    uint32_t r = u + 0x7fffu + ((u >> 16) & 1u);
    return (unsigned short)(r >> 16);
}

// ---------------- Pass 1a: dequant W -> bf16 [N][K]
__global__ void dequant_w_kernel(const int* __restrict__ w,
                                 const float* __restrict__ absmax,
                                 unsigned short* __restrict__ W,
                                 long long n8) {
    long long i = (long long)blockIdx.x * blockDim.x + threadIdx.x;
    long long stride = (long long)gridDim.x * blockDim.x;
    for (; i < n8; i += stride) {
        const int4* p = (const int4*)(w + i * 8);
        int4 v0 = p[0], v1 = p[1];
        float s = absmax[i >> 3];
        union { unsigned short u[8]; float4 v; } out;
        out.u[0] = f32_to_bf16_rne(NF4_CODE_C[v0.x] * s);
        out.u[1] = f32_to_bf16_rne(NF4_CODE_C[v0.y] * s);
        out.u[2] = f32_to_bf16_rne(NF4_CODE_C[v0.z] * s);
        out.u[3] = f32_to_bf16_rne(NF4_CODE_C[v0.w] * s);
        out.u[4] = f32_to_bf16_rne(NF4_CODE_C[v1.x] * s);
        out.u[5] = f32_to_bf16_rne(NF4_CODE_C[v1.y] * s);
        out.u[6] = f32_to_bf16_rne(NF4_CODE_C[v1.z] * s);
        out.u[7] = f32_to_bf16_rne(NF4_CODE_C[v1.w] * s);
        *(float4*)(W + i * 8) = out.v;
    }
}

// ---------------- Pass 1b: x fp32 -> bf16
__global__ void cvt_x_kernel(const float* __restrict__ x,
                             unsigned short* __restrict__ xb,
                             long long n8) {
    long long i = (long long)blockIdx.x * blockDim.x + threadIdx.x;
    long long stride = (long long)gridDim.x * blockDim.x;
    for (; i < n8; i += stride) {
        const float4* p = (const float4*)(x + i * 8);
        float4 a = p[0], b = p[1];
        union { unsigned short u[8]; float4 v; } out;
        out.u[0] = f32_to_bf16_rne(a.x);
        out.u[1] = f32_to_bf16_rne(a.y);
        out.u[2] = f32_to_bf16_rne(a.z);
        out.u[3] = f32_to_bf16_rne(a.w);
        out.u[4] = f32_to_bf16_rne(b.x);
        out.u[5] = f32_to_bf16_rne(b.y);
        out.u[6] = f32_to_bf16_rne(b.z);
        out.u[7] = f32_to_bf16_rne(b.w);
        *(float4*)(xb + i * 8) = out.v;
    }
}

// ---------------- Pass 2: distance-3 pipelined bf16 GEMM (B^T), 256x256 tile,
// BK=32, 4 LDS buffers (128 KiB), 8 waves (2M x 4N), wave tile 128x64.
// Every dependency is >=1 full K-tile distant:
//  - MFMAs consume frags pre-read during the PREVIOUS tile (zero lgkm stall)
//  - tile-end VMW(4) waits on loads issued TWO tiles ago (zero vm stall)
//  - ONE barrier per K-tile.
// Ledger invariant (per-wave, 4 loads/tile): entering tile t, outstanding =
// {t+2's 4}; body stages t+3 (->8); VMW(4) forces t+2, leaves t+3. Frags of
// tile t+1 are read in body t, guaranteed by body(t-1)'s VMW (forced <=t+1)
// + BAR. WAR: ST(t+3) overwrites buf holding tile t-1, whose reads finished
// before body(t-2)'s BAR. Addressing identical to r3 (HW-proven: absmax 0.5,
// 0 bank conflicts).
__device__ __forceinline__ void llds16(const unsigned short* g, unsigned short* l) {
    __builtin_amdgcn_global_load_lds(
        (const __attribute__((address_space(1))) unsigned int*)g,
        (__attribute__((address_space(3))) unsigned int*)l,
        16, 0, 0);
}

#define GK 4096
#define GN 14336

__global__ void __launch_bounds__(512, 2)
gemm_d3_bf16(const unsigned short* __restrict__ A,  // [M][4096] bf16 bits
             const unsigned short* __restrict__ B,  // [14336][4096] bf16 bits
             const float* __restrict__ bias,
             float* __restrict__ C, int Mtiles) {
    // 4 buffers x (A 256x32 + B 256x32) bf16 = 4 x 32KB = 128 KiB
    __shared__ unsigned short lds[65536];
    const int tid  = threadIdx.x;
    const int lane = tid & 63;
    const int wv   = tid >> 6;        // wave 0..7
    const int wr   = wv >> 2;         // M half
    const int wc   = wv & 3;          // N quarter

    // T1: bijective XCD swizzle (m204)
    const int nwg = gridDim.x;
    const int q = nwg >> 3, r = nwg & 7;
    const int xcd = blockIdx.x & 7, loc = blockIdx.x >> 3;
    const int s = (xcd < r ? xcd * (q + 1) : r * (q + 1) + (xcd - r) * q) + loc;
    const int tm = s % Mtiles;
    const int tn = s / Mtiles;
    const int brow = tm * 256;
    const int bcol = tn * 256;

    f32x4 acc[8][4] = {};

    // staging (r3-proven): thread T -> row T>>2, LDS slot T&3 linear,
    // global 16B-chunk pre-swizzled: (T&3) ^ ((T>>3)&3)   [T2, rule #21]
    const int srow   = tid >> 2;
    const int gchunk = (tid & 3) ^ ((tid >> 3) & 3);
    const unsigned short* pA = A + (size_t)(brow + srow) * GK + gchunk * 8;
    const unsigned short* pB = B + (size_t)(bcol + srow) * GK + gchunk * 8;

    // read offsets (r3-proven): slot = (lane>>4) ^ (((lane&15)>>1)&3)
    const int kqs  = (((lane >> 4) ^ (((lane & 15) >> 1) & 3))) * 8;
    const int aoff = (wr * 128 + (lane & 15)) * 32 + kqs;
    const int boff = 8192 + (wc * 64 + (lane & 15)) * 32 + kqs;

#define ST_ALL(T, O) do {                                             \
        const unsigned short* a0 = pA + (size_t)(T) * 32;             \
        const unsigned short* b0 = pB + (size_t)(T) * 32;             \
        unsigned short* l = &lds[(O) + wv * 512];                     \
        llds16(a0,            l);                                     \
        llds16(a0 + 128 * GK, l + 4096);                              \
        llds16(b0,            l + 8192);                              \
        llds16(b0 + 128 * GK, l + 12288);                             \
    } while (0)

#define RD_ALL(AF, BQ, O) do {                                        \
        _Pragma("unroll")                                             \
        for (int i = 0; i < 8; ++i) AF[i] = *(const short8*)&lds[(O) + aoff + i * 512]; \
        _Pragma("unroll")                                             \
        for (int n = 0; n < 4; ++n) BQ[n] = *(const short8*)&lds[(O) + boff + n * 512]; \
    } while (0)

#define MM_ALL(AF, BQ) do {                                           \
        __builtin_amdgcn_s_setprio(1);                                \
        _Pragma("unroll")                                             \
        for (int i = 0; i < 8; ++i)                                   \
            _Pragma("unroll")                                         \
            for (int n = 0; n < 4; ++n)                               \
                acc[i][n] = __builtin_amdgcn_mfma_f32_16x16x32_bf16(  \
                    AF[i], BQ[n], acc[i][n], 0, 0, 0);                \
        __builtin_amdgcn_s_setprio(0);                                \
    } while (0)

#define VMW(N) asm volatile("s_waitcnt vmcnt(" #N ")" ::: "memory")
#define BAR()  __builtin_amdgcn_s_barrier()

    short8 af0[8], bq0[4], af1[8], bq1[4];

    // prologue: stage tiles 0,1,2 -> bufs 0,1,2; force t0,t1; pre-read t0
    ST_ALL(0, 0); ST_ALL(1, 16384); ST_ALL(2, 32768);
    VMW(4); BAR();
    RD_ALL(af0, bq0, 0);

    // main: tiles 0..123 (NT = 4096/32 = 128); body(t): RD t+1, ST t+3, MM t
    #pragma unroll 1
    for (int t = 0; t < 124; t += 4) {
        RD_ALL(af1, bq1, 16384); ST_ALL(t + 3, 49152); MM_ALL(af0, bq0); VMW(4); BAR();
        RD_ALL(af0, bq0, 32768); ST_ALL(t + 4, 0);     MM_ALL(af1, bq1); VMW(4); BAR();
        RD_ALL(af1, bq1, 49152); ST_ALL(t + 5, 16384); MM_ALL(af0, bq0); VMW(4); BAR();
        RD_ALL(af0, bq0, 0);     ST_ALL(t + 6, 32768); MM_ALL(af1, bq1); VMW(4); BAR();
    }
    // tail: tiles 124..127
    RD_ALL(af1, bq1, 16384); ST_ALL(127, 49152); MM_ALL(af0, bq0); VMW(4); BAR();
    RD_ALL(af0, bq0, 32768);                     MM_ALL(af1, bq1); VMW(0); BAR();
    RD_ALL(af1, bq1, 49152);                     MM_ALL(af0, bq0);
    MM_ALL(af1, bq1);

#undef ST_ALL
#undef RD_ALL
#undef MM_ALL
#undef VMW
#undef BAR

    // epilogue: D col = lane&15, row = (lane>>4)*4 + j  [verified layout]
    #pragma unroll
    for (int n = 0; n < 4; ++n) {
        const int col = bcol + wc * 64 + n * 16 + (lane & 15);
        const float bv = bias[col];
        #pragma unroll
        for (int i = 0; i < 8; ++i) {
            #pragma unroll
            for (int j = 0; j < 4; ++j) {
                const int row = brow + wr * 128 + i * 16 + (lane >> 4) * 4 + j;
                C[(size_t)row * GN + col] = acc[i][n][j] + bv;
            }
        }
    }
}

// ---------------- fallback: naive fused fp32
__global__ void naive_fused(const float* __restrict__ x, const int* __restrict__ w,
                            const float* __restrict__ am, const float* __restrict__ bias,
                            float* __restrict__ out, int M) {
    long long o = (long long)blockIdx.x * blockDim.x + threadIdx.x;
    if (o >= (long long)M * OUT_F) return;
    int m = (int)(o / OUT_F), n = (int)(o % OUT_F);
    const int* wr_ = w + (size_t)n * IN_F;
    const float* xr = x + (size_t)m * IN_F;
    const float* amr = am + (size_t)n * (IN_F / QBLK);
    float sum = 0.f;
    for (int k = 0; k < IN_F; ++k)
        sum += xr[k] * NF4_CODE_C[wr_[k]] * amr[k >> 6];
    out[o] = sum + bias[n];
}

extern "C" void kernel_launch(void* const* d_in, const int* in_sizes, int n_in,
                              void* d_out, int out_size, void* d_ws, size_t ws_size,
                              hipStream_t stream) {
    const float* x      = (const float*)d_in[0];
    const int*   w_idx  = (const int*)d_in[1];
    const float* absmax = (const float*)d_in[2];
    const float* bias   = (const float*)d_in[3];
    float* out = (float*)d_out;

    const int M = in_sizes[0] / IN_F;   // 4096
    const int N = OUT_F;                // 14336
    const int K = IN_F;                 // 4096

    const size_t needW = (size_t)N * K * 2;
    const size_t needX = (size_t)M * K * 2;
    if (ws_size >= needW + needX && (M % 256) == 0) {
        unsigned short* Wb = (unsigned short*)d_ws;
        unsigned short* Xb = (unsigned short*)((char*)d_ws + needW);

        long long n8w = (long long)N * K / 8;
        dequant_w_kernel<<<8192, 256, 0, stream>>>(w_idx, absmax, Wb, n8w);
        long long n8x = (long long)M * K / 8;
        cvt_x_kernel<<<4096, 256, 0, stream>>>(x, Xb, n8x);

        const int Mtiles = M / 256;
        dim3 grid(Mtiles * (N / 256));
        gemm_d3_bf16<<<grid, 512, 0, stream>>>(Xb, Wb, bias, out, Mtiles);
    } else {
        long long total = (long long)M * OUT_F;
        int blocks = (int)((total + 255) / 256);
        naive_fused<<<blocks, 256, 0, stream>>>(x, w_idx, absmax, bias, out, M);
    }
}

// Round 8
// 529.294 us; speedup vs baseline: 1.1598x; 1.1598x over previous
//
#include <hip/hip_runtime.h>
#include <stdint.h>

#define IN_F 4096
#define OUT_F 14336
#define QBLK 64

__device__ __constant__ float NF4_CODE_C[16] = {
    -1.0f, -0.6961928009986877f, -0.5250730514526367f, -0.39491748809814453f,
    -0.28444138169288635f, -0.18477343022823334f, -0.09105003625154495f, 0.0f,
    0.07958029955625534f, 0.16093020141124725f, 0.24611230194568634f,
    0.33791524171829224f, 0.44070982933044434f, 0.5626170039176941f,
    0.8333911895751953f, 1.0f};

typedef __attribute__((ext_vector_type(8))) short short8;   // 8 bf16 (4 VGPRs)
typedef __attribute__((ext_vector_type(4))) float f32x4;    // MFMA acc

__device__ __forceinline__ unsigned short f32_to_bf16_rne(float f) {
    union { float f; uint32_t u; } a; a.f = f;
    uint32_t u = a.u;
    uint32_t r = u + 0x7fffu + ((u >> 16) & 1u);
    return (unsigned short)(r >> 16);
}

// ---------------- Pass 1a: dequant W -> bf16 [N][K]
__global__ void dequant_w_kernel(const int* __restrict__ w,
                                 const float* __restrict__ absmax,
                                 unsigned short* __restrict__ W,
                                 long long n8) {
    long long i = (long long)blockIdx.x * blockDim.x + threadIdx.x;
    long long stride = (long long)gridDim.x * blockDim.x;
    for (; i < n8; i += stride) {
        const int4* p = (const int4*)(w + i * 8);
        int4 v0 = p[0], v1 = p[1];
        float s = absmax[i >> 3];
        union { unsigned short u[8]; float4 v; } out;
        out.u[0] = f32_to_bf16_rne(NF4_CODE_C[v0.x] * s);
        out.u[1] = f32_to_bf16_rne(NF4_CODE_C[v0.y] * s);
        out.u[2] = f32_to_bf16_rne(NF4_CODE_C[v0.z] * s);
        out.u[3] = f32_to_bf16_rne(NF4_CODE_C[v0.w] * s);
        out.u[4] = f32_to_bf16_rne(NF4_CODE_C[v1.x] * s);
        out.u[5] = f32_to_bf16_rne(NF4_CODE_C[v1.y] * s);
        out.u[6] = f32_to_bf16_rne(NF4_CODE_C[v1.z] * s);
        out.u[7] = f32_to_bf16_rne(NF4_CODE_C[v1.w] * s);
        *(float4*)(W + i * 8) = out.v;
    }
}

// ---------------- Pass 1b: x fp32 -> bf16
__global__ void cvt_x_kernel(const float* __restrict__ x,
                             unsigned short* __restrict__ xb,
                             long long n8) {
    long long i = (long long)blockIdx.x * blockDim.x + threadIdx.x;
    long long stride = (long long)gridDim.x * blockDim.x;
    for (; i < n8; i += stride) {
        const float4* p = (const float4*)(x + i * 8);
        float4 a = p[0], b = p[1];
        union { unsigned short u[8]; float4 v; } out;
        out.u[0] = f32_to_bf16_rne(a.x);
        out.u[1] = f32_to_bf16_rne(a.y);
        out.u[2] = f32_to_bf16_rne(a.z);
        out.u[3] = f32_to_bf16_rne(a.w);
        out.u[4] = f32_to_bf16_rne(b.x);
        out.u[5] = f32_to_bf16_rne(b.y);
        out.u[6] = f32_to_bf16_rne(b.z);
        out.u[7] = f32_to_bf16_rne(b.w);
        *(float4*)(xb + i * 8) = out.v;
    }
}

// ---------------- Pass 2: r4 dataflow, relaxed sync: 2 VMW+BAR per K-tile.
// 256x256 tile, BK=64, 2 LDS buffers (128 KiB), 8 waves (2M x 4N), wave tile
// 128x64. Stage groups: L1(t+1)={A0,A2,B00,B10} issued ph1(t) (feeds ph1
// reads af0/bq0); L2(t+1)={B01,B11,A1,A3} issued ph2(t) (feeds ph2/ph3 reads
// bq1/af1). Sync: end-ph1 VMW(4)+BAR (forces+publishes L2(t), leaves L1(t+1));
// end-ph4 VMW(4)+BAR (forces+publishes L1(t+1), WAR-protects buffer swap).
// Wait distance = 3 phases (~550cy) > HBM latency slack vs r4's 2. Phases
// 2-4 are barrier-free (48 MFMA + 6 ds_reads, waves slide).
__device__ __forceinline__ void llds16(const unsigned short* g, unsigned short* l) {
    __builtin_amdgcn_global_load_lds(
        (const __attribute__((address_space(1))) unsigned int*)g,
        (__attribute__((address_space(3))) unsigned int*)l,
        16, 0, 0);
}

#define GK 4096
#define GN 14336

__global__ void __launch_bounds__(512, 2)
gemm_2sync_bf16(const unsigned short* __restrict__ A,  // [M][4096] bf16 bits
                const unsigned short* __restrict__ B,  // [14336][4096] bf16 bits
                const float* __restrict__ bias,
                float* __restrict__ C, int Mtiles) {
    __shared__ unsigned short lds[65536];
    const int tid  = threadIdx.x;
    const int lane = tid & 63;
    const int wv   = tid >> 6;        // wave 0..7
    const int wr   = wv >> 2;         // M half
    const int wc   = wv & 3;          // N quarter

    // T1: bijective XCD swizzle (m204)
    const int nwg = gridDim.x;
    const int q = nwg >> 3, r = nwg & 7;
    const int xcd = blockIdx.x & 7, loc = blockIdx.x >> 3;
    const int s = (xcd < r ? xcd * (q + 1) : r * (q + 1) + (xcd - r) * q) + loc;
    const int tm = s % Mtiles;
    const int tn = s / Mtiles;
    const int brow = tm * 256;
    const int bcol = tn * 256;

    f32x4 acc[8][4] = {};

    // staging (r3/r4-proven): lane l: row += l>>3, LDS slot l&7 linear,
    // global 16B-chunk pre-swizzled gch = (l&7)^((l>>3)&7)  [T2, rule #21]
    const int l8 = lane >> 3, l7 = lane & 7;
    const int gch = (l7 ^ (l8 & 7)) * 8;
    const unsigned short* pA = A + (size_t)(brow + wv * 8 + l8) * GK + gch;
    const unsigned short* pB = B + (size_t)(bcol + (wv >> 2) * 64 + (wv & 3) * 8 + l8) * GK + gch;
    const int ldsA = wv * 512;
    const int ldsB = 16384 + (wv >> 2) * 4096 + (wv & 3) * 512;

    // read offsets (r4-proven): slot = (kgrp + 4*kk) ^ (row&7)
    const int sl0 = (((lane >> 4)    ) ^ l7) * 8;
    const int sl1 = (((lane >> 4) + 4) ^ l7) * 8;
    const int ab = (wr * 128 + (lane & 15)) * 64;
    const int bb = 16384 + (wc * 64 + (lane & 15)) * 64;

#define ST_A(c, T, O)    llds16(pA + (size_t)(c) * 64 * GK + (size_t)(T) * 64, &lds[(O) + (c) * 4096 + ldsA])
#define ST_B(P, qq, T, O) llds16(pB + (size_t)((P) * 128 + (qq) * 32) * GK + (size_t)(T) * 64, &lds[(O) + (P) * 8192 + (qq) * 2048 + ldsB])

#define RD_A(af, qm, O) do { _Pragma("unroll")                                  \
    for (int rt = 0; rt < 4; ++rt) {                                            \
        af[rt][0] = *(const short8*)&lds[(O) + ab + (qm) * 4096 + rt * 1024 + sl0]; \
        af[rt][1] = *(const short8*)&lds[(O) + ab + (qm) * 4096 + rt * 1024 + sl1]; \
    } } while (0)
#define RD_B(bq, qn, O) do { _Pragma("unroll")                                  \
    for (int nt = 0; nt < 2; ++nt) {                                            \
        bq[nt][0] = *(const short8*)&lds[(O) + bb + (qn) * 2048 + nt * 1024 + sl0]; \
        bq[nt][1] = *(const short8*)&lds[(O) + bb + (qn) * 2048 + nt * 1024 + sl1]; \
    } } while (0)
#define MM(af, bq, i0, n0) do {                                                 \
    __builtin_amdgcn_s_setprio(1);                                              \
    _Pragma("unroll") for (int rt = 0; rt < 4; ++rt)                            \
    _Pragma("unroll") for (int nt = 0; nt < 2; ++nt)                            \
    _Pragma("unroll") for (int kk = 0; kk < 2; ++kk)                            \
        acc[(i0) + rt][(n0) + nt] = __builtin_amdgcn_mfma_f32_16x16x32_bf16(    \
            af[rt][kk], bq[nt][kk], acc[(i0) + rt][(n0) + nt], 0, 0, 0);        \
    __builtin_amdgcn_s_setprio(0);                                              \
} while (0)

#define VMW(N) asm volatile("s_waitcnt vmcnt(" #N ")" ::: "memory")
#define BAR()  __builtin_amdgcn_s_barrier()

// compute tile from O, stage tile T into NO. 2 sync points (end-ph1, end-ph4).
#define TILE_BODY(O, NO, T) do {                                                \
    short8 af0[4][2], af1[4][2], bq0[2][2], bq1[2][2];                          \
    /* ph1: stage L1(T) = {A0,A2,B00,B10}; compute (qm0,qn0) */                 \
    ST_A(0, T, NO); ST_A(2, T, NO); ST_B(0, 0, T, NO); ST_B(1, 0, T, NO);       \
    RD_A(af0, 0, O); RD_B(bq0, 0, O);                                           \
    MM(af0, bq0, 0, 0);                                                         \
    VMW(4); BAR();   /* forces+publishes L2(t); leaves L1(T) in flight */       \
    /* ph2: stage L2(T) = {B01,B11,A1,A3}; compute (qm0,qn1) */                 \
    ST_B(0, 1, T, NO); ST_B(1, 1, T, NO); ST_A(1, T, NO); ST_A(3, T, NO);       \
    RD_B(bq1, 1, O);                                                            \
    MM(af0, bq1, 0, 2);                                                         \
    /* ph3: compute (qm1,qn0) */                                                \
    RD_A(af1, 1, O);                                                            \
    MM(af1, bq0, 4, 0);                                                         \
    /* ph4: compute (qm1,qn1) */                                                \
    MM(af1, bq1, 4, 2);                                                         \
    VMW(4); BAR();   /* forces+publishes L1(T); WAR-protect */                  \
} while (0)

    // prologue: L1(0), L2(0) -> buf0; force L1(0), leave L2(0) in flight
    ST_A(0, 0, 0); ST_A(2, 0, 0); ST_B(0, 0, 0, 0); ST_B(1, 0, 0, 0);
    ST_B(0, 1, 0, 0); ST_B(1, 1, 0, 0); ST_A(1, 0, 0); ST_A(3, 0, 0);
    VMW(4); BAR();

    // main: tiles 0..62 stage their successor (NT = 64)
    #pragma unroll 1
    for (int t = 0; t < 62; t += 2) {
        TILE_BODY(0,     32768, t + 1);
        TILE_BODY(32768, 0,     t + 2);
    }
    TILE_BODY(0, 32768, 63);   // tile 62, stages tile 63

    { // tail: tile 63 from buf1, no staging
        short8 af0[4][2], af1[4][2], bq0[2][2], bq1[2][2];
        RD_A(af0, 0, 32768); RD_B(bq0, 0, 32768);
        MM(af0, bq0, 0, 0);
        VMW(0); BAR();   // force+publish L2(63)
        RD_B(bq1, 1, 32768);
        MM(af0, bq1, 0, 2);
        RD_A(af1, 1, 32768);
        MM(af1, bq0, 4, 0);
        MM(af1, bq1, 4, 2);
    }

#undef TILE_BODY
#undef VMW
#undef BAR
#undef MM
#undef RD_A
#undef RD_B
#undef ST_A
#undef ST_B

    // epilogue: D col = lane&15, row = (lane>>4)*4 + j  [verified layout]
    #pragma unroll
    for (int n = 0; n < 4; ++n) {
        const int col = bcol + wc * 64 + n * 16 + (lane & 15);
        const float bv = bias[col];
        #pragma unroll
        for (int i = 0; i < 8; ++i) {
            #pragma unroll
            for (int j = 0; j < 4; ++j) {
                const int row = brow + wr * 128 + i * 16 + (lane >> 4) * 4 + j;
                C[(size_t)row * GN + col] = acc[i][n][j] + bv;
            }
        }
    }
}

// ---------------- fallback: naive fused fp32
__global__ void naive_fused(const float* __restrict__ x, const int* __restrict__ w,
                            const float* __restrict__ am, const float* __restrict__ bias,
                            float* __restrict__ out, int M) {
    long long o = (long long)blockIdx.x * blockDim.x + threadIdx.x;
    if (o >= (long long)M * OUT_F) return;
    int m = (int)(o / OUT_F), n = (int)(o % OUT_F);
    const int* wr_ = w + (size_t)n * IN_F;
    const float* xr = x + (size_t)m * IN_F;
    const float* amr = am + (size_t)n * (IN_F / QBLK);
    float sum = 0.f;
    for (int k = 0; k < IN_F; ++k)
        sum += xr[k] * NF4_CODE_C[wr_[k]] * amr[k >> 6];
    out[o] = sum + bias[n];
}

extern "C" void kernel_launch(void* const* d_in, const int* in_sizes, int n_in,
                              void* d_out, int out_size, void* d_ws, size_t ws_size,
                              hipStream_t stream) {
    const float* x      = (const float*)d_in[0];
    const int*   w_idx  = (const int*)d_in[1];
    const float* absmax = (const float*)d_in[2];
    const float* bias   = (const float*)d_in[3];
    float* out = (float*)d_out;

    const int M = in_sizes[0] / IN_F;   // 4096
    const int N = OUT_F;                // 14336
    const int K = IN_F;                 // 4096

    const size_t needW = (size_t)N * K * 2;
    const size_t needX = (size_t)M * K * 2;
    if (ws_size >= needW + needX && (M % 256) == 0) {
        unsigned short* Wb = (unsigned short*)d_ws;
        unsigned short* Xb = (unsigned short*)((char*)d_ws + needW);

        long long n8w = (long long)N * K / 8;
        dequant_w_kernel<<<8192, 256, 0, stream>>>(w_idx, absmax, Wb, n8w);
        long long n8x = (long long)M * K / 8;
        cvt_x_kernel<<<4096, 256, 0, stream>>>(x, Xb, n8x);

        const int Mtiles = M / 256;
        dim3 grid(Mtiles * (N / 256));
        gemm_2sync_bf16<<<grid, 512, 0, stream>>>(Xb, Wb, bias, out, Mtiles);
    } else {
        long long total = (long long)M * OUT_F;
        int blocks = (int)((total + 255) / 256);
        naive_fused<<<blocks, 256, 0, stream>>>(x, w_idx, absmax, bias, out, M);
    }
}